// Round 3
// baseline (653.404 us; speedup 1.0000x reference)
//
#include <hip/hip_runtime.h>
#include <hip/hip_bf16.h>
#include <stdint.h>

// y[b,s,o] = sum_i x[b,s,i] * (w[o,i]*mask[o,i]) + bias[o]
// Inputs fp32: x [4,2048,4096], w [4096,4096], bias [4096], mask [4096,4096].
// Output fp32 [8192,4096]. Compute: bf16 MFMA (tolerance is bf16-floor).
// M = 8192, N = 4096, K = 4096.
#define M_DIM 8192
#define N_DIM 4096
#define K_DIM 4096
#define BM 128
#define BN 128
#define BK 32
#define KP (K_DIM / BK)          // 128 k-panels
#define PANEL_U4 512             // 16B chunks per 8KB panel (128 rows x 32 bf16)

typedef __attribute__((ext_vector_type(8))) __bf16 bf16x8;
typedef __attribute__((ext_vector_type(4))) float floatx4;

// ---------- fp32 -> bf16 (RNE) ----------
__device__ inline unsigned f2b(float f) {
    union { float f; unsigned u; } v; v.f = f;
    return (v.u + 0x7FFFu + ((v.u >> 16) & 1u)) >> 16;   // RNE; inputs finite
}
__device__ inline unsigned pk2(float lo, float hi) {
    return (f2b(lo) & 0xFFFFu) | (f2b(hi) << 16);
}
__device__ inline uint4 pk8(float4 a, float4 b) {
    uint4 o;
    o.x = pk2(a.x, a.y); o.y = pk2(a.z, a.w);
    o.z = pk2(b.x, b.y); o.w = pk2(b.z, b.w);
    return o;
}

// Async global->LDS, 16B/lane. LDS dest is wave-uniform base + lane*16
// (linear!), so the swizzle lives in the GLOBAL panel layout instead.
__device__ inline void async_load16(const void* g, void* l) {
    __builtin_amdgcn_global_load_lds(
        (const __attribute__((address_space(1))) unsigned int*)(unsigned long long)g,
        (__attribute__((address_space(3))) unsigned int*)(unsigned int)(unsigned long long)l,
        16, 0, 0);
}

// ---------- Pass 1 (fused): x -> bf16 panels, wb = bf16(w*mask) panels ----
// Panel layout: panel p = tile*KP + kpanel, 512 chunks of 16B.
// Chunk (row r4 in tile, ksub 0..3) stored at slot r4*4 + (ksub ^ ((r4>>1)&3)).
// This makes GEMM fragment ds_read_b128 exactly 2-way bank-aliased (free).
__global__ __launch_bounds__(256)
void cvt_pack_kernel(const float* __restrict__ x,
                     const float* __restrict__ w,
                     const float* __restrict__ mask,
                     uint4* __restrict__ xb, uint4* __restrict__ wb) {
    const int NX = M_DIM * K_DIM / 8;   // 4,194,304 x-chunks
    int tid = blockIdx.x * 256 + threadIdx.x;
    if (tid < NX) {
        const int cx = tid;
        const int p = cx >> 9, s = cx & 511;
        const int r4 = s >> 2, perm = s & 3;
        const int ksub = perm ^ ((r4 >> 1) & 3);
        const int rt = p >> 7, kp = p & (KP - 1);
        const size_t src = (size_t)(rt * BM + r4) * K_DIM + kp * BK + ksub * 8;
        float4 a = *(const float4*)(x + src);
        float4 b = *(const float4*)(x + src + 4);
        xb[cx] = pk8(a, b);
    } else {
        const int cw = tid - NX;        // < 2,097,152
        const int p = cw >> 9, s = cw & 511;
        const int r4 = s >> 2, perm = s & 3;
        const int ksub = perm ^ ((r4 >> 1) & 3);
        const int nt = p >> 7, kp = p & (KP - 1);
        const size_t src = (size_t)(nt * BN + r4) * K_DIM + kp * BK + ksub * 8;
        float4 a = *(const float4*)(w + src);
        float4 b = *(const float4*)(w + src + 4);
        float4 qa = *(const float4*)(mask + src);
        float4 qb = *(const float4*)(mask + src + 4);
        a.x *= qa.x; a.y *= qa.y; a.z *= qa.z; a.w *= qa.w;
        b.x *= qb.x; b.y *= qb.y; b.z *= qb.z; b.w *= qb.w;
        wb[cw] = pk8(a, b);
    }
}

// ---------- Pass 2: C = A @ B^T + bias from swizzled bf16 panels ----------
__global__ __launch_bounds__(256)
void gemm_bt_bias(const uint4* __restrict__ Apan,    // [64][KP][512] chunks
                  const uint4* __restrict__ Bpan,    // [32][KP][512] chunks
                  const float* __restrict__ bias,
                  float* __restrict__ C) {
    __shared__ __hip_bfloat16 As[BM * BK];   // 8 KB
    __shared__ __hip_bfloat16 Bs[BN * BK];   // 8 KB

    const int t    = threadIdx.x;
    const int lane = t & 63;
    const int wave = t >> 6;
    const int wm   = wave >> 1;
    const int wn   = wave & 1;
    const int m0   = blockIdx.y * BM;
    const int n0   = blockIdx.x * BN;

    const int lm   = lane & 15;
    // Read-side swizzle: chunk (r4, ksub=lane>>4) lives at slot r4*4+perm,
    // perm = ksub ^ ((r4>>1)&3); with r4 = 16*i + lm this is i-independent:
    const int perm = ((lane >> 4) ^ ((lane >> 1) & 3)) & 3;

    floatx4 acc[4][4] = {};

    const int c0 = t, c1 = t + 256;
    const uint4* ap = Apan + ((size_t)blockIdx.y * KP) * PANEL_U4;
    const uint4* bp = Bpan + ((size_t)blockIdx.x * KP) * PANEL_U4;

    const __hip_bfloat16* aF = As + (((wm * 64 + lm) * 4 + perm) * 8);
    const __hip_bfloat16* bF = Bs + (((wn * 64 + lm) * 4 + perm) * 8);

    for (int kp = 0; kp < KP; kp++) {
        async_load16(ap + c0, As + c0 * 8);
        async_load16(ap + c1, As + c1 * 8);
        async_load16(bp + c0, Bs + c0 * 8);
        async_load16(bp + c1, Bs + c1 * 8);
        ap += PANEL_U4; bp += PANEL_U4;
        __syncthreads();   // drains vmcnt -> staged tiles visible

        bf16x8 af[4], bfr[4];
#pragma unroll
        for (int i = 0; i < 4; i++) af[i]  = *(const bf16x8*)(aF + i * 512);
#pragma unroll
        for (int j = 0; j < 4; j++) bfr[j] = *(const bf16x8*)(bF + j * 512);
#pragma unroll
        for (int i = 0; i < 4; i++)
#pragma unroll
            for (int j = 0; j < 4; j++)
                acc[i][j] = __builtin_amdgcn_mfma_f32_16x16x32_bf16(
                    af[i], bfr[j], acc[i][j], 0, 0, 0);
        __syncthreads();
    }

    // Epilogue. C/D layout: col = lane&15, row = (lane>>4)*4 + reg.
    float bv[4];
#pragma unroll
    for (int j = 0; j < 4; j++)
        bv[j] = bias[n0 + wn * 64 + j * 16 + lm];
    const int row_base = m0 + wm * 64 + (lane >> 4) * 4;
    const int col_base = n0 + wn * 64 + lm;
#pragma unroll
    for (int i = 0; i < 4; i++)
#pragma unroll
        for (int j = 0; j < 4; j++) {
            const int col = col_base + j * 16;
#pragma unroll
            for (int r = 0; r < 4; r++)
                C[(size_t)(row_base + i * 16 + r) * N_DIM + col] =
                    acc[i][j][r] + bv[j];
        }
}

// ---------- Fallback (ws too small): fuse cvt+mask into staging ----------
__global__ __launch_bounds__(256)
void gemm_fused_f32(const float* __restrict__ A, const float* __restrict__ W,
                    const float* __restrict__ Mk, const float* __restrict__ bias,
                    float* __restrict__ C) {
    __shared__ __hip_bfloat16 As[BM * BK];
    __shared__ __hip_bfloat16 Bs[BN * BK];
    const int t = threadIdx.x, lane = t & 63, wave = t >> 6;
    const int wm = wave >> 1, wn = wave & 1;
    const int m0 = blockIdx.y * BM, n0 = blockIdx.x * BN;
    const int lm = lane & 15, lk = (lane >> 4) << 3;
    floatx4 acc[4][4] = {};
    const int r = t >> 1, cb = (t & 1) * 16;
    for (int k0 = 0; k0 < K_DIM; k0 += BK) {
        const float* ap = A + (size_t)(m0 + r) * K_DIM + k0 + cb;
        float4 f0 = ((const float4*)ap)[0], f1 = ((const float4*)ap)[1];
        float4 f2 = ((const float4*)ap)[2], f3 = ((const float4*)ap)[3];
        *(uint4*)&As[r * BK + cb] = pk8(f0, f1);
        *(uint4*)&As[r * BK + cb + 8] = pk8(f2, f3);
        const float* wp = W + (size_t)(n0 + r) * K_DIM + k0 + cb;
        const float* mp = Mk + (size_t)(n0 + r) * K_DIM + k0 + cb;
        float4 w0 = ((const float4*)wp)[0], w1 = ((const float4*)wp)[1];
        float4 w2 = ((const float4*)wp)[2], w3 = ((const float4*)wp)[3];
        float4 q0 = ((const float4*)mp)[0], q1 = ((const float4*)mp)[1];
        float4 q2 = ((const float4*)mp)[2], q3 = ((const float4*)mp)[3];
        w0.x*=q0.x; w0.y*=q0.y; w0.z*=q0.z; w0.w*=q0.w;
        w1.x*=q1.x; w1.y*=q1.y; w1.z*=q1.z; w1.w*=q1.w;
        w2.x*=q2.x; w2.y*=q2.y; w2.z*=q2.z; w2.w*=q2.w;
        w3.x*=q3.x; w3.y*=q3.y; w3.z*=q3.z; w3.w*=q3.w;
        *(uint4*)&Bs[r * BK + cb] = pk8(w0, w1);
        *(uint4*)&Bs[r * BK + cb + 8] = pk8(w2, w3);
        __syncthreads();
        bf16x8 af[4], bfr[4];
#pragma unroll
        for (int i = 0; i < 4; i++)
            af[i] = *(const bf16x8*)(&As[(wm * 64 + i * 16 + lm) * BK + lk]);
#pragma unroll
        for (int j = 0; j < 4; j++)
            bfr[j] = *(const bf16x8*)(&Bs[(wn * 64 + j * 16 + lm) * BK + lk]);
#pragma unroll
        for (int i = 0; i < 4; i++)
#pragma unroll
            for (int j = 0; j < 4; j++)
                acc[i][j] = __builtin_amdgcn_mfma_f32_16x16x32_bf16(
                    af[i], bfr[j], acc[i][j], 0, 0, 0);
        __syncthreads();
    }
    float bv[4];
#pragma unroll
    for (int j = 0; j < 4; j++) bv[j] = bias[n0 + wn * 64 + j * 16 + lm];
    const int row_base = m0 + wm * 64 + (lane >> 4) * 4;
    const int col_base = n0 + wn * 64 + lm;
#pragma unroll
    for (int i = 0; i < 4; i++)
#pragma unroll
        for (int j = 0; j < 4; j++) {
            const int col = col_base + j * 16;
#pragma unroll
            for (int r4 = 0; r4 < 4; r4++)
                C[(size_t)(row_base + i * 16 + r4) * N_DIM + col] =
                    acc[i][j][r4] + bv[j];
        }
}

extern "C" void kernel_launch(void* const* d_in, const int* in_sizes, int n_in,
                              void* d_out, int out_size, void* d_ws, size_t ws_size,
                              hipStream_t stream) {
    const float* x    = (const float*)d_in[0];
    const float* w    = (const float*)d_in[1];
    const float* bias = (const float*)d_in[2];
    const float* mask = (const float*)d_in[3];
    float* out = (float*)d_out;

    const size_t xb_bytes = (size_t)M_DIM * K_DIM * 2;   // 64 MiB
    const size_t wb_bytes = (size_t)N_DIM * K_DIM * 2;   // 32 MiB
    dim3 grid(N_DIM / BN, M_DIM / BM);   // 32 x 64
    dim3 block(256);

    if (ws_size >= xb_bytes + wb_bytes) {
        uint4* xb = (uint4*)d_ws;
        uint4* wb = (uint4*)((char*)d_ws + xb_bytes);
        const int nchunks = (M_DIM * K_DIM + N_DIM * K_DIM) / 8;  // 6,291,456
        cvt_pack_kernel<<<dim3(nchunks / 256), block, 0, stream>>>(
            x, w, mask, xb, wb);
        gemm_bt_bias<<<grid, block, 0, stream>>>(xb, wb, bias, out);
    } else {
        gemm_fused_f32<<<grid, block, 0, stream>>>(x, w, mask, bias, out);
    }
}